// Round 1
// baseline (200.780 us; speedup 1.0000x reference)
//
#include <hip/hip_runtime.h>

// DeltaSynapse: I[b,o] = sum_{d,e} s_e*W[e,o]*delaymap[d,e,o]*Xd[d,b,e]*(1+Wshort[d,b,e])
// Exploit Xd sparsity (~2%): compact nonzero (e, coef) lists per (d,b), then
// scatter-accumulate c * W[e,:] * delaymap[d,e,:] into I[b,:].

constexpr int D = 8, B = 16, E = 2048, O = 2048;
constexpr int DB = D * B;
constexpr int OTILE = 1024;           // o-columns per block
constexpr int THREADS2 = OTILE / 4;   // 256 threads, float4 per thread
constexpr int ESPLIT = 2;             // split entry list across blocks for parallelism

struct Entry { int e; float c; };

// ---------------- Pass 1: build per-(d,b) compacted spike lists ----------------
__global__ __launch_bounds__(256) void build_lists(
    const float* __restrict__ Xd, const float* __restrict__ Wshort,
    const int* __restrict__ signs, int* __restrict__ counts,
    Entry* __restrict__ entries)
{
    const int db = blockIdx.x;              // db = d*B + b
    __shared__ int cnt;
    if (threadIdx.x == 0) cnt = 0;
    __syncthreads();
    const float* xrow = Xd + (size_t)db * E;
    const float* wsr  = Wshort + (size_t)db * E;
    Entry* out = entries + (size_t)db * E;
    for (int e = threadIdx.x; e < E; e += blockDim.x) {
        float x = xrow[e];
        if (x != 0.0f) {
            float s = (float)(2 * signs[e] - 1);   // {0,1} -> {-1,+1}
            float c = x * s * (1.0f + wsr[e]);
            int slot = atomicAdd(&cnt, 1);         // shared-mem atomic, order irrelevant
            out[slot].e = e;
            out[slot].c = c;
        }
    }
    __syncthreads();
    if (threadIdx.x == 0) counts[db] = cnt;
}

// ---------------- Pass 2: scatter-accumulate into I ----------------
__global__ __launch_bounds__(THREADS2) void accum(
    const float* __restrict__ W, const float* __restrict__ dm,
    const int* __restrict__ counts, const Entry* __restrict__ entries,
    float* __restrict__ Iout)
{
    const int tile = blockIdx.x;            // 0 .. O/OTILE-1
    const int part = blockIdx.y;            // 0 .. ESPLIT-1
    const int db   = blockIdx.z;            // 0 .. DB-1
    const int d = db / B;
    const int b = db % B;
    const int o0 = tile * OTILE + (int)threadIdx.x * 4;

    const int n = counts[db];
    const Entry* __restrict__ lst = entries + (size_t)db * E;

    float4 acc = make_float4(0.f, 0.f, 0.f, 0.f);
    #pragma unroll 2
    for (int i = part; i < n; i += ESPLIT) {
        Entry en = lst[i];
        const float4 w = *(const float4*)(W  + (size_t)en.e * O + o0);
        const float4 m = *(const float4*)(dm + ((size_t)d * E + en.e) * O + o0);
        acc.x += en.c * w.x * m.x;
        acc.y += en.c * w.y * m.y;
        acc.z += en.c * w.z * m.z;
        acc.w += en.c * w.w * m.w;
    }

    float* orow = Iout + (size_t)b * O + o0;
#if defined(__HIP_DEVICE_COMPILE__)
    unsafeAtomicAdd(orow + 0, acc.x);   // HW global_atomic_add_f32
    unsafeAtomicAdd(orow + 1, acc.y);
    unsafeAtomicAdd(orow + 2, acc.z);
    unsafeAtomicAdd(orow + 3, acc.w);
#endif
}

extern "C" void kernel_launch(void* const* d_in, const int* in_sizes, int n_in,
                              void* d_out, int out_size, void* d_ws, size_t ws_size,
                              hipStream_t stream) {
    const float* W     = (const float*)d_in[0];   // (E, O)
    const float* Xd    = (const float*)d_in[1];   // (D, B, E)
    const float* dm    = (const float*)d_in[2];   // (D, E, O)
    const float* Wsh   = (const float*)d_in[3];   // (D, B, E)
    const int*   signs = (const int*)d_in[4];     // (E,)
    float* Iout = (float*)d_out;                  // (B, O) fp32

    // workspace: counts[DB] ints at 0, Entry[DB][E] at +512 (needs ~2 MB)
    int*   counts  = (int*)d_ws;
    Entry* entries = (Entry*)((char*)d_ws + 512);

    hipMemsetAsync(d_out, 0, sizeof(float) * (size_t)B * O, stream);
    build_lists<<<dim3(DB), dim3(256), 0, stream>>>(Xd, Wsh, signs, counts, entries);
    dim3 grid(O / OTILE, ESPLIT, DB);
    accum<<<grid, dim3(THREADS2), 0, stream>>>(W, dm, counts, entries, Iout);
}

// Round 2
// 198.518 us; speedup vs baseline: 1.0114x; 1.0114x over previous
//
#include <hip/hip_runtime.h>

// DeltaSynapse: I[b,o] = sum_{d,e} s_e*W[e,o]*delaymap[d,e,o]*Xd[d,b,e]*(1+Wshort[d,b,e])
// Xd is ~2% sparse: pass1 compacts nonzero (e, coef) per (d,b); pass2 accumulates
// c * W[e,:] * delaymap[d,e,:] into per-(d,part) partial slices (no atomics);
// pass3 reduces the 32 slices into I.

constexpr int D = 8, B = 16, E = 2048, O = 2048;
constexpr int DB = D * B;
constexpr int OTILE = 512;            // o-columns per block
constexpr int THREADS2 = OTILE / 4;   // 128 threads, float4 per thread
constexpr int ESPLIT = 4;             // split entry list across blocks
constexpr int NSLICE = D * ESPLIT;    // 32 partial slices

struct Entry { int e; float c; };

// ---------------- Pass 1: build per-(d,b) compacted spike lists ----------------
__global__ __launch_bounds__(256) void build_lists(
    const float* __restrict__ Xd, const float* __restrict__ Wshort,
    const int* __restrict__ signs, int* __restrict__ counts,
    Entry* __restrict__ entries)
{
    const int db = blockIdx.x;              // db = d*B + b
    __shared__ int cnt;
    if (threadIdx.x == 0) cnt = 0;
    __syncthreads();
    const float* xrow = Xd + (size_t)db * E;
    const float* wsr  = Wshort + (size_t)db * E;
    Entry* out = entries + (size_t)db * E;
    for (int e = threadIdx.x; e < E; e += blockDim.x) {
        float x = xrow[e];
        if (x != 0.0f) {
            float s = (float)(2 * signs[e] - 1);   // {0,1} -> {-1,+1}
            float c = x * s * (1.0f + wsr[e]);
            int slot = atomicAdd(&cnt, 1);         // shared-mem atomic, order irrelevant
            out[slot].e = e;
            out[slot].c = c;
        }
    }
    __syncthreads();
    if (threadIdx.x == 0) counts[db] = cnt;
}

// ---------------- Pass 2: accumulate into partial slices ----------------
__global__ __launch_bounds__(THREADS2) void accum(
    const float* __restrict__ W, const float* __restrict__ dm,
    const int* __restrict__ counts, const Entry* __restrict__ entries,
    float* __restrict__ partial)
{
    const int tile = blockIdx.x;            // 0 .. O/OTILE-1
    const int part = blockIdx.y;            // 0 .. ESPLIT-1
    const int db   = blockIdx.z;            // 0 .. DB-1
    const int d = db >> 4;                  // db / B
    const int b = db & 15;                  // db % B
    const int o0 = tile * OTILE + (int)threadIdx.x * 4;

    const int n = counts[db];
    const Entry* __restrict__ lst = entries + (size_t)db * E;

    // Stage this block's strided entry subset contiguously in LDS.
    __shared__ Entry sh[E / ESPLIT];        // up to 512 entries, 4 KB
    for (int j = threadIdx.x; part + j * ESPLIT < n; j += THREADS2)
        sh[j] = lst[part + j * ESPLIT];
    const int m = (n - part + ESPLIT - 1) / ESPLIT;   // #entries for this part (>=0)
    __syncthreads();

    const float* __restrict__ dmd = dm + (size_t)d * E * O;
    float4 acc = make_float4(0.f, 0.f, 0.f, 0.f);
    #pragma unroll 4
    for (int j = 0; j < m; ++j) {
        Entry en = sh[j];
        const float4 w  = *(const float4*)(W   + (size_t)en.e * O + o0);
        const float4 mm = *(const float4*)(dmd + (size_t)en.e * O + o0);
        acc.x += en.c * w.x * mm.x;
        acc.y += en.c * w.y * mm.y;
        acc.z += en.c * w.z * mm.z;
        acc.w += en.c * w.w * mm.w;
    }

    // Unconditional full-coverage write -> no pre-zeroing needed.
    float* p = partial + ((size_t)(d * ESPLIT + part) * B + b) * O + o0;
    *(float4*)p = acc;
}

// ---------------- Pass 3: reduce 32 slices -> I ----------------
__global__ __launch_bounds__(256) void reduce_slices(
    const float* __restrict__ partial, float* __restrict__ Iout)
{
    const int bo = blockIdx.x * 256 + threadIdx.x;    // 0 .. B*O-1
    float s = 0.f;
    #pragma unroll
    for (int k = 0; k < NSLICE; ++k)
        s += partial[(size_t)k * B * O + bo];
    Iout[bo] = s;
}

extern "C" void kernel_launch(void* const* d_in, const int* in_sizes, int n_in,
                              void* d_out, int out_size, void* d_ws, size_t ws_size,
                              hipStream_t stream) {
    const float* W     = (const float*)d_in[0];   // (E, O)
    const float* Xd    = (const float*)d_in[1];   // (D, B, E)
    const float* dm    = (const float*)d_in[2];   // (D, E, O)
    const float* Wsh   = (const float*)d_in[3];   // (D, B, E)
    const int*   signs = (const int*)d_in[4];     // (E,)
    float* Iout = (float*)d_out;                  // (B, O) fp32

    // workspace layout:
    //   [0, 512)            counts[DB]
    //   [512, 512+2MB)      entries[DB][E]
    //   [4MB, 8MB)          partial[NSLICE][B][O]
    int*   counts  = (int*)d_ws;
    Entry* entries = (Entry*)((char*)d_ws + 512);
    float* partial = (float*)((char*)d_ws + (4u << 20));

    build_lists<<<dim3(DB), dim3(256), 0, stream>>>(Xd, Wsh, signs, counts, entries);
    dim3 grid(O / OTILE, ESPLIT, DB);
    accum<<<grid, dim3(THREADS2), 0, stream>>>(W, dm, counts, entries, partial);
    reduce_slices<<<dim3(B * O / 256), dim3(256), 0, stream>>>(partial, Iout);
}